// Round 7
// baseline (85.295 us; speedup 1.0000x reference)
//
#include <hip/hip_runtime.h>

#define N_KPS 1024
#define N_PTS 120000
#define BLOCK 256                 // 4 waves per block
#define KSPLIT 4                  // one wave per K-chunk -> 7500 waves (7.3/SIMD)
#define KCHUNK (N_KPS / KSPLIT)   // 256 ctrl points per wave

// r6 post-mortem: fitting r2's counters gives v_log_f32 ~16 cyc/wave64 (1/8
// VALU rate), blocking the SIMD issue pipe -> per-pair floor is 7 VALU x 2cyc
// + 1 trans x 16cyc = 30 cyc/64 pairs, IDENTICAL for scalar and pk forms (pk
// f32 is half-rate). So: drop all packing (kills VOP3P broadcast-mov risk —
// scalar ops take kx/wx directly as their one SGPR operand), keep split-K
// occupancy (the only change that ever helped), fold the zero-guard into the
// d2 fma chain. Model: 7.32 waves/SIMD x 256 ctrl x 30 cyc ~ 56k cyc ~ 23us.
#if __has_builtin(__builtin_amdgcn_logf)
#define RAW_LOG2(x) __builtin_amdgcn_logf(x)   // bare v_log_f32 (= log2)
#else
#define RAW_LOG2(x) __log2f(x)
#endif

__global__ __launch_bounds__(BLOCK) void tps_warp_kernel(
    const float2* __restrict__ pts,
    const float*  __restrict__ kps,
    const float*  __restrict__ W,
    float2*       __restrict__ out)
{
    __shared__ float2 part[KSPLIT][64];

    const int lane = threadIdx.x & 63;
    // Provably wave-uniform wave id -> ctrl-chunk base stays uniform -> the
    // kps/W reads below compile to s_load batches (SGPRs, scalar cache).
    const int wv = __builtin_amdgcn_readfirstlane(threadIdx.x) >> 6;

    const int j = blockIdx.x * 64 + lane;     // 1875*64 == 120000, exact cover
    const float2 p = pts[j];

    float zx = 0.0f, zy = 0.0f;

    const int i0 = wv * KCHUNK;
    #pragma unroll 8
    for (int i = i0; i < i0 + KCHUNK; ++i) {
        // Uniform indices -> scalar loads; each value below is an SGPR used
        // directly as the single allowed SGPR operand of its VALU op: no movs.
        float kx = kps[2 * i];
        float ky = kps[2 * i + 1];
        float wx = W[2 * i];
        float wy = W[2 * i + 1];

        float dx = kx - p.x;                       // v_sub
        float dy = ky - p.y;                       // v_sub
        // +1e-37 folds the d2==0 guard into the chain: d2=0 -> 1e-37 ->
        // v = 1e-37*log2(1e-37) ~ 0, matching reference's where(l2==0, 1.0)
        // -> 0.5*1*ln(1) = 0. Also keeps log input above the denormal range.
        float d2 = fmaf(dy, dy, fmaf(dx, dx, 1e-37f));   // 2x v_fma
        float t  = RAW_LOG2(d2);                   // v_log_f32 (trans, ~16cyc)
        float v  = d2 * t;                         // v_mul; 0.5*ln2 at epilogue
        zx = fmaf(v, wx, zx);                      // v_fma
        zy = fmaf(v, wy, zy);                      // v_fma
    }

    part[wv][lane] = make_float2(zx, zy);
    __syncthreads();

    if (wv == 0) {
        float2 a = part[0][lane];
        float2 b = part[1][lane];
        float2 c = part[2][lane];
        float2 d = part[3][lane];
        float sx = (a.x + b.x) + (c.x + d.x);
        float sy = (a.y + b.y) + (c.y + d.y);

        const float scale = 0.34657359027997264f;  // 0.5 * ln(2)
        float w1x = W[2048], w1y = W[2049];
        float wxx = W[2050], wxy = W[2051];
        float wyx = W[2052], wyy = W[2053];

        float ox = p.x + fmaf(scale, sx, fmaf(wxx, p.x, fmaf(wyx, p.y, w1x)));
        float oy = p.y + fmaf(scale, sy, fmaf(wxy, p.x, fmaf(wyy, p.y, w1y)));
        out[j] = make_float2(ox, oy);
    }
}

extern "C" void kernel_launch(void* const* d_in, const int* in_sizes, int n_in,
                              void* d_out, int out_size, void* d_ws, size_t ws_size,
                              hipStream_t stream) {
    const float* pts = (const float*)d_in[0];   // [120000, 2]
    const float* kps = (const float*)d_in[1];   // [1024, 2]
    const float* W   = (const float*)d_in[2];   // [1027, 2]
    float* out = (float*)d_out;                 // [120000, 2]

    const int grid = N_PTS / 64;                // 1875, exact
    tps_warp_kernel<<<grid, BLOCK, 0, stream>>>(
        (const float2*)pts, kps, W, (float2*)out);
}